// Round 1
// baseline (489.588 us; speedup 1.0000x reference)
//
#include <hip/hip_runtime.h>

// VectorQuantizer: N=32*4096=131072 tokens, D=64, K=1024 codes.
// out layout (float32, concatenated): [0,8388608) quant, [8388608] loss,
// [8388609, 8519681) encoding indices (as float).
//
// Strategy: fp32 vector (no fp32 MFMA on CDNA4). One token per lane;
// embedding read via wave-uniform loads -> SMEM pipe (s_load), leaving the
// VALU free for the 64-FMA dot chain. Numerics mimic the numpy reference:
// sequential-FMA dot (BLAS k-loop order), numpy pairwise-8 row sums for
// |x|^2 and |e|^2, score = fl(x2+e2[k]) - 2*dot (scale by 2 is exact),
// strict < with ascending k == argmin first-occurrence tie-break.

#define KC 1024
#define DD 64
#define NTOK (32 * 4096)
#define QUANT_ELEMS ((size_t)NTOK * DD)        // 8388608
#define LOSS_OFF QUANT_ELEMS                   // 8388608
#define IDX_OFF (QUANT_ELEMS + 1)              // 8388609

// ws layout: ws[0..1023] = |e_k|^2 table, ws[1024] = loss accumulator

__global__ void vq_prep(const float* __restrict__ emb, float* __restrict__ ws) {
  int k = blockIdx.x * blockDim.x + threadIdx.x;
  if (k == 0) ws[KC] = 0.0f;  // zero loss accumulator (ws is poisoned 0xAA)
  if (k < KC) {
    const float* e = emb + (size_t)k * DD;
    // numpy pairwise-8 summation of e[d]^2 (squares rounded individually)
    float r[8];
#pragma unroll
    for (int j = 0; j < 8; ++j) r[j] = e[j] * e[j];
#pragma unroll
    for (int i = 1; i < 8; ++i) {
#pragma unroll
      for (int j = 0; j < 8; ++j) {
        float v = e[i * 8 + j];
        r[j] += v * v;
      }
    }
    ws[k] = ((r[0] + r[1]) + (r[2] + r[3])) + ((r[4] + r[5]) + (r[6] + r[7]));
  }
}

__launch_bounds__(256)
__global__ void vq_main(const float* __restrict__ x_in,
                        const float* __restrict__ emb,
                        const float* __restrict__ e2tab,
                        float* __restrict__ out,
                        float* __restrict__ loss_acc) {
  const int token = blockIdx.x * 256 + threadIdx.x;  // grid covers NTOK exactly

  // Load this lane's token (64 floats) into registers.
  const float* xp = x_in + (size_t)token * DD;
  float x[DD];
#pragma unroll
  for (int i = 0; i < 16; ++i) {
    float4 v = ((const float4*)xp)[i];
    x[4 * i + 0] = v.x; x[4 * i + 1] = v.y;
    x[4 * i + 2] = v.z; x[4 * i + 3] = v.w;
  }

  // |x|^2 via numpy pairwise-8
  float r[8];
#pragma unroll
  for (int j = 0; j < 8; ++j) r[j] = x[j] * x[j];
#pragma unroll
  for (int i = 1; i < 8; ++i) {
#pragma unroll
    for (int j = 0; j < 8; ++j) r[j] += x[i * 8 + j] * x[i * 8 + j];
  }
  const float x2 = ((r[0] + r[1]) + (r[2] + r[3])) + ((r[4] + r[5]) + (r[6] + r[7]));

  // Argmin over codes. emb/e2tab indices are wave-uniform -> scalar loads.
  float best = 3.402823466e38f;
  int bidx = 0;
  for (int k = 0; k < KC; ++k) {
    const float* e = emb + (size_t)k * DD;
    float dot = 0.0f;
#pragma unroll
    for (int d = 0; d < DD; ++d) dot = __builtin_fmaf(x[d], e[d], dot);
    // distances = (input_sq + embed_sq) - (2.0 * dot); 2*dot is exact
    float d2 = (x2 + e2tab[k]) - 2.0f * dot;
    if (d2 < best) { best = d2; bidx = k; }  // strict <: first-min wins ties
  }

  // Outputs: index (as float), quant row (bitwise embedding copy), loss part.
  out[IDX_OFF + (size_t)token] = (float)bidx;

  const float* eq = emb + (size_t)bidx * DD;  // divergent gather, L2-hot
  float* op = out + (size_t)token * DD;
  float err = 0.0f;
#pragma unroll
  for (int i = 0; i < 16; ++i) {
    float4 v = ((const float4*)eq)[i];
    float d0 = v.x - x[4 * i + 0];
    float d1 = v.y - x[4 * i + 1];
    float d2v = v.z - x[4 * i + 2];
    float d3 = v.w - x[4 * i + 3];
    err = __builtin_fmaf(d0, d0, err);
    err = __builtin_fmaf(d1, d1, err);
    err = __builtin_fmaf(d2v, d2v, err);
    err = __builtin_fmaf(d3, d3, err);
    ((float4*)op)[i] = v;
  }

  // wave(64)-level reduction, one atomic per wave
#pragma unroll
  for (int off = 32; off > 0; off >>= 1) err += __shfl_down(err, off);
  if ((threadIdx.x & 63) == 0) atomicAdd(loss_acc, err);
}

__global__ void vq_finish(const float* __restrict__ acc, float* __restrict__ out) {
  float m = acc[0] / (float)QUANT_ELEMS;  // mean squared error
  out[LOSS_OFF] = m + 0.25f * m;          // q_latent + COMMITMENT_COST * e_latent
}

extern "C" void kernel_launch(void* const* d_in, const int* in_sizes, int n_in,
                              void* d_out, int out_size, void* d_ws, size_t ws_size,
                              hipStream_t stream) {
  const float* x = (const float*)d_in[0];
  const float* emb = (const float*)d_in[1];
  float* out = (float*)d_out;
  float* ws = (float*)d_ws;

  vq_prep<<<4, 256, 0, stream>>>(emb, ws);
  vq_main<<<NTOK / 256, 256, 0, stream>>>(x, emb, ws, out, ws + KC);
  vq_finish<<<1, 1, 0, stream>>>(ws + KC, out);
}

// Round 2
// 467.294 us; speedup vs baseline: 1.0477x; 1.0477x over previous
//
#include <hip/hip_runtime.h>

// VectorQuantizer: N=131072 tokens, D=64, K=1024 codes.
// out (float32 concat): [0,8388608) quant, [8388608] loss, [8388609,...) idx.
//
// R2 structure: x held in VGPRs (2 tokens/lane, __launch_bounds__(256,2) to
// stop the backend's occupancy heuristic from demoting x to scratch — R1
// showed VGPR=44 + 34MB of scratch writes). Embedding row is wave-uniform ->
// s_load into SGPRs (R1 SGPR=96 confirms), so the hot loop is pure
// v_fma_f32 with one SGPR operand. K split in 2 across blockIdx.y for
// 2 waves/SIMD; combine kernel merges (low half wins ties == ascending-k
// first-min). All FMA chains ordered exactly as the R1 kernel that passed.

#define KC 1024
#define DD 64
#define NTOK (32 * 4096)
#define QUANT_ELEMS ((size_t)NTOK * DD)        // 8388608
#define LOSS_OFF QUANT_ELEMS                   // 8388608
#define IDX_OFF (QUANT_ELEMS + 1)              // 8388609

// ws layout (float words):
// [0,1024)              e2 table
// [1024]                loss accumulator
// [2048, 2048+2*NTOK)   best-d2  (half0 then half1)
// [2048+2*NTOK, +4*NTOK) best-idx (int, half0 then half1)
#define WS_E2 0
#define WS_LOSS 1024
#define WS_D2 2048
#define WS_IDX (2048 + 2 * NTOK)

__global__ void vq_prep(const float* __restrict__ emb, float* __restrict__ ws) {
  int k = blockIdx.x * blockDim.x + threadIdx.x;
  if (k == 0) ws[WS_LOSS] = 0.0f;  // ws is poisoned 0xAA each launch
  if (k < KC) {
    const float* e = emb + (size_t)k * DD;
    // numpy pairwise-8 summation of e[d]^2
    float r[8];
#pragma unroll
    for (int j = 0; j < 8; ++j) r[j] = e[j] * e[j];
#pragma unroll
    for (int i = 1; i < 8; ++i) {
#pragma unroll
      for (int j = 0; j < 8; ++j) {
        float v = e[i * 8 + j];
        r[j] += v * v;
      }
    }
    ws[WS_E2 + k] = ((r[0] + r[1]) + (r[2] + r[3])) + ((r[4] + r[5]) + (r[6] + r[7]));
  }
}

__launch_bounds__(256, 2)
__global__ void vq_dist(const float* __restrict__ x_in,
                        const float* __restrict__ emb,
                        const float* __restrict__ e2tab,
                        float* __restrict__ d2_out,
                        int* __restrict__ idx_out) {
  const int tid = threadIdx.x;
  const int t0 = blockIdx.x * 512 + tid;   // token A
  const int t1 = t0 + 256;                 // token B
  const int kbase = blockIdx.y * (KC / 2); // K half

  float x0[DD], x1[DD];
  {
    const float4* p0 = (const float4*)(x_in + (size_t)t0 * DD);
    const float4* p1 = (const float4*)(x_in + (size_t)t1 * DD);
#pragma unroll
    for (int i = 0; i < 16; ++i) {
      float4 a = p0[i];
      x0[4 * i + 0] = a.x; x0[4 * i + 1] = a.y; x0[4 * i + 2] = a.z; x0[4 * i + 3] = a.w;
      float4 b = p1[i];
      x1[4 * i + 0] = b.x; x1[4 * i + 1] = b.y; x1[4 * i + 2] = b.z; x1[4 * i + 3] = b.w;
    }
  }

  // |x|^2 via numpy pairwise-8 (identical for both K-halves -> comparable)
  float x20, x21;
  {
    float r[8];
#pragma unroll
    for (int j = 0; j < 8; ++j) r[j] = x0[j] * x0[j];
#pragma unroll
    for (int i = 1; i < 8; ++i)
#pragma unroll
      for (int j = 0; j < 8; ++j) r[j] += x0[i * 8 + j] * x0[i * 8 + j];
    x20 = ((r[0] + r[1]) + (r[2] + r[3])) + ((r[4] + r[5]) + (r[6] + r[7]));
#pragma unroll
    for (int j = 0; j < 8; ++j) r[j] = x1[j] * x1[j];
#pragma unroll
    for (int i = 1; i < 8; ++i)
#pragma unroll
      for (int j = 0; j < 8; ++j) r[j] += x1[i * 8 + j] * x1[i * 8 + j];
    x21 = ((r[0] + r[1]) + (r[2] + r[3])) + ((r[4] + r[5]) + (r[6] + r[7]));
  }

  float best0 = 3.402823466e38f, best1 = 3.402823466e38f;
  int bi0 = kbase, bi1 = kbase;
#pragma unroll 2
  for (int k = kbase; k < kbase + KC / 2; ++k) {
    const float* e = emb + (size_t)k * DD;  // wave-uniform -> s_load
    float d0 = 0.0f, d1 = 0.0f;
#pragma unroll
    for (int d = 0; d < DD; ++d) {
      float ev = e[d];
      d0 = __builtin_fmaf(x0[d], ev, d0);
      d1 = __builtin_fmaf(x1[d], ev, d1);
    }
    float e2 = e2tab[k];
    float s0 = (x20 + e2) - 2.0f * d0;
    float s1 = (x21 + e2) - 2.0f * d1;
    if (s0 < best0) { best0 = s0; bi0 = k; }  // strict <: first-min wins
    if (s1 < best1) { best1 = s1; bi1 = k; }
  }

  const size_t ho = (size_t)blockIdx.y * NTOK;
  d2_out[ho + t0] = best0;
  d2_out[ho + t1] = best1;
  idx_out[ho + t0] = bi0;
  idx_out[ho + t1] = bi1;
}

__global__ void vq_combine(const float* __restrict__ x_in,
                           const float* __restrict__ emb,
                           const float* __restrict__ d2w,
                           const int* __restrict__ idxw,
                           float* __restrict__ out,
                           float* __restrict__ loss_acc) {
  const int t = blockIdx.x * 256 + threadIdx.x;
  float dl = d2w[t], dh = d2w[NTOK + t];
  int il = idxw[t], ih = idxw[NTOK + t];
  int bidx = (dh < dl) ? ih : il;  // strict: low half (smaller k) wins ties

  out[IDX_OFF + (size_t)t] = (float)bidx;

  const float* eq = emb + (size_t)bidx * DD;   // gather, L2-hot (256 KB table)
  const float* xp = x_in + (size_t)t * DD;
  float* op = out + (size_t)t * DD;
  float err = 0.0f;
#pragma unroll
  for (int i = 0; i < 16; ++i) {
    float4 v = ((const float4*)eq)[i];
    float4 xv = ((const float4*)xp)[i];
    float d0 = v.x - xv.x;
    float d1 = v.y - xv.y;
    float d2v = v.z - xv.z;
    float d3 = v.w - xv.w;
    err = __builtin_fmaf(d0, d0, err);
    err = __builtin_fmaf(d1, d1, err);
    err = __builtin_fmaf(d2v, d2v, err);
    err = __builtin_fmaf(d3, d3, err);
    ((float4*)op)[i] = v;  // bitwise embedding copy
  }

#pragma unroll
  for (int off = 32; off > 0; off >>= 1) err += __shfl_down(err, off);
  if ((threadIdx.x & 63) == 0) atomicAdd(loss_acc, err);
}

__global__ void vq_finish(const float* __restrict__ acc, float* __restrict__ out) {
  float m = acc[0] / (float)QUANT_ELEMS;
  out[LOSS_OFF] = m + 0.25f * m;  // q_latent + COMMITMENT_COST * e_latent
}

extern "C" void kernel_launch(void* const* d_in, const int* in_sizes, int n_in,
                              void* d_out, int out_size, void* d_ws, size_t ws_size,
                              hipStream_t stream) {
  const float* x = (const float*)d_in[0];
  const float* emb = (const float*)d_in[1];
  float* out = (float*)d_out;
  float* ws = (float*)d_ws;

  vq_prep<<<4, 256, 0, stream>>>(emb, ws);
  dim3 gdist(NTOK / 512, 2);
  vq_dist<<<gdist, 256, 0, stream>>>(x, emb, ws + WS_E2,
                                     ws + WS_D2, (int*)(ws + WS_IDX));
  vq_combine<<<NTOK / 256, 256, 0, stream>>>(x, emb, ws + WS_D2,
                                             (int*)(ws + WS_IDX), out,
                                             ws + WS_LOSS);
  vq_finish<<<1, 1, 0, stream>>>(ws + WS_LOSS, out);
}

// Round 3
// 366.299 us; speedup vs baseline: 1.3366x; 1.2757x over previous
//
#include <hip/hip_runtime.h>

// VectorQuantizer: N=131072 tokens, D=64, K=1024 codes.
// out (float32 concat): [0,8388608) quant, [8388608] loss, [8388609,...) idx.
//
// R3: R2's counters showed the dist kernel is stall-bound on the wave-uniform
// e-row s_loads (~170 exposed cyc/iter) with occupancy capped by GRID size
// (512 blocks = 2/CU). Fix: 1 token/lane, K split 8 ways -> 4096 blocks,
// ~5 blocks/CU resident -> ~5 waves/SIMD to hide the scalar-load latency.
// Partial argmins merge via packed u64 atomicMin: key=(sortable-float<<32)|k,
// lexicographic min == first-min over ascending k on bitwise-identical scores
// (all splits compute the identical (x2+e2[k])-2*dot expression).

#define KC 1024
#define DD 64
#define NTOK (32 * 4096)
#define KSPLIT 8
#define QUANT_ELEMS ((size_t)NTOK * DD)        // 8388608
#define LOSS_OFF QUANT_ELEMS                   // 8388608
#define IDX_OFF (QUANT_ELEMS + 1)              // 8388609

// ws layout (float words): [0,1024) e2 table | [1024] loss acc
// byte offset 8192: packed u64[NTOK] running (dist,idx) min
#define WS_E2 0
#define WS_LOSS 1024
#define WS_PACKED_FLOATOFF 2048

__device__ __forceinline__ unsigned int sortable_bits(float f) {
  unsigned int b = __float_as_uint(f);
  return b ^ (unsigned int)(((int)b >> 31) | 0x80000000);
}

__global__ void vq_init(const float* __restrict__ emb, float* __restrict__ ws,
                        unsigned long long* __restrict__ packed) {
  int t = blockIdx.x * 256 + threadIdx.x;
  packed[t] = ~0ULL;                     // +inf key
  if (t == 0) ws[WS_LOSS] = 0.0f;        // ws poisoned 0xAA each launch
  if (t < KC) {
    const float* e = emb + (size_t)t * DD;
    // numpy pairwise-8 summation of e[d]^2
    float r[8];
#pragma unroll
    for (int j = 0; j < 8; ++j) r[j] = e[j] * e[j];
#pragma unroll
    for (int i = 1; i < 8; ++i)
#pragma unroll
      for (int j = 0; j < 8; ++j) {
        float v = e[i * 8 + j];
        r[j] += v * v;
      }
    ws[WS_E2 + t] = ((r[0] + r[1]) + (r[2] + r[3])) + ((r[4] + r[5]) + (r[6] + r[7]));
  }
}

__launch_bounds__(256, 2)
__global__ void vq_dist(const float* __restrict__ x_in,
                        const float* __restrict__ emb,
                        const float* __restrict__ e2tab,
                        unsigned long long* __restrict__ packed) {
  const int t = blockIdx.x * 256 + threadIdx.x;
  const int kbase = blockIdx.y * (KC / KSPLIT);

  // token into registers (1 token/lane -> ~64 VGPRs for x, fits 5 waves/SIMD)
  float x[DD];
  {
    const float4* p = (const float4*)(x_in + (size_t)t * DD);
#pragma unroll
    for (int i = 0; i < 16; ++i) {
      float4 a = p[i];
      x[4 * i + 0] = a.x; x[4 * i + 1] = a.y;
      x[4 * i + 2] = a.z; x[4 * i + 3] = a.w;
    }
  }

  // |x|^2 via numpy pairwise-8 (bitwise identical across all K-splits)
  float x2;
  {
    float r[8];
#pragma unroll
    for (int j = 0; j < 8; ++j) r[j] = x[j] * x[j];
#pragma unroll
    for (int i = 1; i < 8; ++i)
#pragma unroll
      for (int j = 0; j < 8; ++j) r[j] += x[i * 8 + j] * x[i * 8 + j];
    x2 = ((r[0] + r[1]) + (r[2] + r[3])) + ((r[4] + r[5]) + (r[6] + r[7]));
  }

  float best = 3.402823466e38f;
  int bidx = kbase;
  for (int k = kbase; k < kbase + KC / KSPLIT; ++k) {
    const float* e = emb + (size_t)k * DD;  // wave-uniform -> s_load
    float dot = 0.0f;
#pragma unroll
    for (int d = 0; d < DD; ++d) dot = __builtin_fmaf(x[d], e[d], dot);
    float s = (x2 + e2tab[k]) - 2.0f * dot;
    if (s < best) { best = s; bidx = k; }  // strict <: first-min wins
  }

  unsigned long long key =
      ((unsigned long long)sortable_bits(best) << 32) | (unsigned int)bidx;
  atomicMin(&packed[t], key);
}

__global__ void vq_combine(const float* __restrict__ x_in,
                           const float* __restrict__ emb,
                           const unsigned long long* __restrict__ packed,
                           float* __restrict__ out,
                           float* __restrict__ loss_acc) {
  const int t = blockIdx.x * 256 + threadIdx.x;
  const int bidx = (int)(unsigned int)packed[t];  // low 32 bits = index

  out[IDX_OFF + (size_t)t] = (float)bidx;

  const float* eq = emb + (size_t)bidx * DD;  // gather, L2-hot (256 KB table)
  const float* xp = x_in + (size_t)t * DD;
  float* op = out + (size_t)t * DD;
  float err = 0.0f;
#pragma unroll
  for (int i = 0; i < 16; ++i) {
    float4 v = ((const float4*)eq)[i];
    float4 xv = ((const float4*)xp)[i];
    float d0 = v.x - xv.x;
    float d1 = v.y - xv.y;
    float d2v = v.z - xv.z;
    float d3 = v.w - xv.w;
    err = __builtin_fmaf(d0, d0, err);
    err = __builtin_fmaf(d1, d1, err);
    err = __builtin_fmaf(d2v, d2v, err);
    err = __builtin_fmaf(d3, d3, err);
    ((float4*)op)[i] = v;  // bitwise embedding copy
  }

  // wave reduce -> per-block LDS reduce -> one atomic per block (512 total)
#pragma unroll
  for (int off = 32; off > 0; off >>= 1) err += __shfl_down(err, off);
  __shared__ float wsum[4];
  const int wid = threadIdx.x >> 6;
  if ((threadIdx.x & 63) == 0) wsum[wid] = err;
  __syncthreads();
  if (threadIdx.x == 0) {
    float s = (wsum[0] + wsum[1]) + (wsum[2] + wsum[3]);
    atomicAdd(loss_acc, s);
  }
}

__global__ void vq_finish(const float* __restrict__ acc, float* __restrict__ out) {
  float m = acc[0] / (float)QUANT_ELEMS;
  out[LOSS_OFF] = m + 0.25f * m;  // q_latent + COMMITMENT_COST * e_latent
}

extern "C" void kernel_launch(void* const* d_in, const int* in_sizes, int n_in,
                              void* d_out, int out_size, void* d_ws, size_t ws_size,
                              hipStream_t stream) {
  const float* x = (const float*)d_in[0];
  const float* emb = (const float*)d_in[1];
  float* out = (float*)d_out;
  float* ws = (float*)d_ws;
  unsigned long long* packed = (unsigned long long*)(ws + WS_PACKED_FLOATOFF);

  vq_init<<<NTOK / 256, 256, 0, stream>>>(emb, ws, packed);
  dim3 gdist(NTOK / 256, KSPLIT);
  vq_dist<<<gdist, 256, 0, stream>>>(x, emb, ws + WS_E2, packed);
  vq_combine<<<NTOK / 256, 256, 0, stream>>>(x, emb, packed, out, ws + WS_LOSS);
  vq_finish<<<1, 1, 0, stream>>>(ws + WS_LOSS, out);
}

// Round 4
// 182.818 us; speedup vs baseline: 2.6780x; 2.0036x over previous
//
#include <hip/hip_runtime.h>

// VectorQuantizer: N=131072 tokens, D=64, K=1024 codes.
// out (f32 concat): [0,8388608) quant, [8388608] loss, [8388609,...) idx.
//
// R4: move the 17.2 GFLOP distance GEMM from the 157-TF fp32 VALU (R3:
// 293 us, issue-bound) to the 2-PF f16 MFMA pipe via split-products:
// x=x_hi+x_lo, e=e_hi+e_lo (fp16 pairs), dot = hi*hi + hi*lo + lo*hi
// (dropped lo*lo ~3e-7 << the ~1e-6 fp32-ordering noise vs np that already
// passed R1-R3). mfma_f32_16x16x32_f16, m89-verified layouts:
//   A[m=lane&15][k=(lane>>4)*8+j], B[n=lane&15][k=(lane>>4)*8+j],
//   C: col(n)=lane&15, row(m)=(lane>>4)*4+reg.
// Block = 256 tokens x 256 codes (N split x4, merged via R3's packed-u64
// atomicMin; lexicographic min == ascending-k first-min). B-fragments
// prebuilt in global, staged once to LDS -> no barriers in the tile loop.
// x2/e2 pairwise-8 np-style; s = fma(-2,dot, x2+e2) == fl((x2+e2)-2dot).

#define KC 1024
#define DD 64
#define NTOK (32 * 4096)
#define NQ 4
#define QUANT_ELEMS ((size_t)NTOK * DD)        // 8388608
#define LOSS_OFF QUANT_ELEMS
#define IDX_OFF (QUANT_ELEMS + 1)

// ws float-word offsets
#define WS_E2 0                      // 1024 f32
#define WS_LOSS 1024                 // 1 f32
#define WS_X2 2048                   // NTOK f32
#define WS_PACKED_F (2048 + NTOK)    // NTOK u64 (262144 f32 words)
#define WS_BFRAG_F (WS_PACKED_F + 2 * NTOK)  // 64 tiles*4 frags*64 lanes*16B = 256 KB

typedef _Float16 f16x8 __attribute__((ext_vector_type(8)));
typedef float f32x4 __attribute__((ext_vector_type(4)));

__device__ __forceinline__ unsigned int sortable_bits(float f) {
  unsigned int b = __float_as_uint(f);
  return b ^ (unsigned int)(((int)b >> 31) | 0x80000000);
}

// np pairwise-8 sum of squares of a 64-float row
__device__ __forceinline__ float row_sumsq_np8(const float* p) {
  float r[8];
#pragma unroll
  for (int j = 0; j < 8; ++j) r[j] = p[j] * p[j];
#pragma unroll
  for (int i = 1; i < 8; ++i)
#pragma unroll
    for (int j = 0; j < 8; ++j) {
      float v = p[i * 8 + j];
      r[j] += v * v;
    }
  return ((r[0] + r[1]) + (r[2] + r[3])) + ((r[4] + r[5]) + (r[6] + r[7]));
}

// blocks [0,512): x2 + packed init; [512,576): B-frag build; [576,580): e2
__global__ void vq_setup(const float* __restrict__ x_in,
                         const float* __restrict__ emb,
                         float* __restrict__ ws) {
  const int b = blockIdx.x;
  const int tid = threadIdx.x;
  if (b < 512) {
    const int t = b * 256 + tid;
    ((unsigned long long*)(ws + WS_PACKED_F))[t] = ~0ULL;
    if (t == 0) ws[WS_LOSS] = 0.0f;
    ws[WS_X2 + t] = row_sumsq_np8(x_in + (size_t)t * DD);
  } else if (b < 576) {
    const int nt = b - 512;            // global tile 0..63 (16 codes each)
    const int f = tid >> 6;            // 0..3: plane(hi/lo) x kstep
    const int lane = tid & 63;
    const int plane = f >> 1, ks = f & 1;
    const int n = nt * 16 + (lane & 15);
    const int kb = ks * 32 + ((lane >> 4) & 3) * 8;
    const float* ep = emb + (size_t)n * DD + kb;
    f16x8 o;
#pragma unroll
    for (int j = 0; j < 8; ++j) {
      float v = ep[j];
      _Float16 h = (_Float16)v;
      o[j] = (plane == 0) ? h : (_Float16)(v - (float)h);
    }
    ((f16x8*)(ws + WS_BFRAG_F))[(nt * 4 + f) * 64 + lane] = o;
  } else {
    const int k = (b - 576) * 256 + tid;  // 0..1023
    ws[WS_E2 + k] = row_sumsq_np8(emb + (size_t)k * DD);
  }
}

__launch_bounds__(256, 2)
__global__ void vq_dist_mfma(const float* __restrict__ x_in,
                             const float* __restrict__ ws_ro,
                             unsigned long long* __restrict__ packed) {
  const int tid = threadIdx.x;
  const int wave = tid >> 6, lane = tid & 63;
  const int quad = lane >> 4, l16 = lane & 15;
  const int q = blockIdx.y;                       // code quarter
  const int tokBase = blockIdx.x * 256 + wave * 64;

  const float* x2g = ws_ro + WS_X2;
  const float* e2g = ws_ro + WS_E2;

  // Stage this quarter's B fragments: 16 tiles * 4 frags * 64 lanes * 16B
  __shared__ float4 Bf[4096];                     // 64 KB
  {
    const float4* bsrc = (const float4*)(ws_ro + WS_BFRAG_F) + (size_t)q * 4096;
#pragma unroll
    for (int i = 0; i < 16; ++i) {
      int slot = i * 256 + tid;
      Bf[slot] = bsrc[slot];
    }
  }

  // A fragments: 4 m-sets of 16 tokens; split x into fp16 hi/lo planes.
  f16x8 ah[4][2], al[4][2];
#pragma unroll
  for (int ms = 0; ms < 4; ++ms) {
    const float* xr = x_in + (size_t)(tokBase + ms * 16 + l16) * DD;
#pragma unroll
    for (int ks = 0; ks < 2; ++ks) {
      const float4* p = (const float4*)(xr + ks * 32 + quad * 8);
      float4 v0 = p[0], v1 = p[1];
      float vv[8] = {v0.x, v0.y, v0.z, v0.w, v1.x, v1.y, v1.z, v1.w};
#pragma unroll
      for (int j = 0; j < 8; ++j) {
        _Float16 h = (_Float16)vv[j];
        ah[ms][ks][j] = h;
        al[ms][ks][j] = (_Float16)(vv[j] - (float)h);
      }
    }
  }

  // x2 for this lane's C rows: token = tokBase + ms*16 + quad*4 + reg
  float x2v[4][4];
#pragma unroll
  for (int ms = 0; ms < 4; ++ms)
#pragma unroll
    for (int r = 0; r < 4; ++r)
      x2v[ms][r] = x2g[tokBase + ms * 16 + quad * 4 + r];

  __syncthreads();  // Bf ready; no barriers after this

  float best[4][4];
  int bidx[4][4];
#pragma unroll
  for (int ms = 0; ms < 4; ++ms)
#pragma unroll
    for (int r = 0; r < 4; ++r) { best[ms][r] = 3.402823466e38f; bidx[ms][r] = 0; }

  const f16x8* bfp = (const f16x8*)Bf;
  for (int nt = 0; nt < 16; ++nt) {
    const int ch = nt * 4;
    f16x8 bh0 = bfp[(ch + 0) * 64 + lane];
    f16x8 bh1 = bfp[(ch + 1) * 64 + lane];
    f16x8 bl0 = bfp[(ch + 2) * 64 + lane];
    f16x8 bl1 = bfp[(ch + 3) * 64 + lane];
    const int ncur = q * 256 + nt * 16 + l16;     // this lane's code column
    const float e2v = e2g[ncur];
#pragma unroll
    for (int ms = 0; ms < 4; ++ms) {
      f32x4 acc = {0.f, 0.f, 0.f, 0.f};
      acc = __builtin_amdgcn_mfma_f32_16x16x32_f16(ah[ms][0], bh0, acc, 0, 0, 0);
      acc = __builtin_amdgcn_mfma_f32_16x16x32_f16(ah[ms][1], bh1, acc, 0, 0, 0);
      acc = __builtin_amdgcn_mfma_f32_16x16x32_f16(al[ms][0], bh0, acc, 0, 0, 0);
      acc = __builtin_amdgcn_mfma_f32_16x16x32_f16(al[ms][1], bh1, acc, 0, 0, 0);
      acc = __builtin_amdgcn_mfma_f32_16x16x32_f16(ah[ms][0], bl0, acc, 0, 0, 0);
      acc = __builtin_amdgcn_mfma_f32_16x16x32_f16(ah[ms][1], bl1, acc, 0, 0, 0);
#pragma unroll
      for (int r = 0; r < 4; ++r) {
        float s = __builtin_fmaf(-2.0f, acc[r], x2v[ms][r] + e2v);
        if (s < best[ms][r]) { best[ms][r] = s; bidx[ms][r] = ncur; }
      }
    }
  }

  // Reduce across the 16 lanes of each quad (packed key: min == first-min).
#pragma unroll
  for (int ms = 0; ms < 4; ++ms)
#pragma unroll
    for (int r = 0; r < 4; ++r) {
      unsigned long long key =
          ((unsigned long long)sortable_bits(best[ms][r]) << 32) |
          (unsigned int)bidx[ms][r];
#pragma unroll
      for (int m = 1; m < 16; m <<= 1) {
        unsigned long long o = __shfl_xor(key, m);
        key = o < key ? o : key;
      }
      if (l16 == 0)
        atomicMin(&packed[tokBase + ms * 16 + quad * 4 + r], key);
    }
}

__global__ void vq_combine(const float* __restrict__ x_in,
                           const float* __restrict__ emb,
                           const unsigned long long* __restrict__ packed,
                           float* __restrict__ out,
                           float* __restrict__ loss_acc) {
  const int t = blockIdx.x * 256 + threadIdx.x;
  const int bidx = (int)(unsigned int)packed[t];

  out[IDX_OFF + (size_t)t] = (float)bidx;

  const float* eq = emb + (size_t)bidx * DD;
  const float* xp = x_in + (size_t)t * DD;
  float* op = out + (size_t)t * DD;
  float err = 0.0f;
#pragma unroll
  for (int i = 0; i < 16; ++i) {
    float4 v = ((const float4*)eq)[i];
    float4 xv = ((const float4*)xp)[i];
    float d0 = v.x - xv.x, d1 = v.y - xv.y, d2v = v.z - xv.z, d3 = v.w - xv.w;
    err = __builtin_fmaf(d0, d0, err);
    err = __builtin_fmaf(d1, d1, err);
    err = __builtin_fmaf(d2v, d2v, err);
    err = __builtin_fmaf(d3, d3, err);
    ((float4*)op)[i] = v;  // bitwise embedding copy
  }

#pragma unroll
  for (int off = 32; off > 0; off >>= 1) err += __shfl_down(err, off);
  __shared__ float wsum[4];
  const int wid = threadIdx.x >> 6;
  if ((threadIdx.x & 63) == 0) wsum[wid] = err;
  __syncthreads();
  if (threadIdx.x == 0)
    atomicAdd(loss_acc, (wsum[0] + wsum[1]) + (wsum[2] + wsum[3]));
}

__global__ void vq_finish(const float* __restrict__ acc, float* __restrict__ out) {
  float m = acc[0] / (float)QUANT_ELEMS;
  out[LOSS_OFF] = m + 0.25f * m;
}

extern "C" void kernel_launch(void* const* d_in, const int* in_sizes, int n_in,
                              void* d_out, int out_size, void* d_ws, size_t ws_size,
                              hipStream_t stream) {
  const float* x = (const float*)d_in[0];
  const float* emb = (const float*)d_in[1];
  float* out = (float*)d_out;
  float* ws = (float*)d_ws;
  unsigned long long* packed = (unsigned long long*)(ws + WS_PACKED_F);

  vq_setup<<<580, 256, 0, stream>>>(x, emb, ws);
  dim3 gdist(NTOK / 256, NQ);
  vq_dist_mfma<<<gdist, 256, 0, stream>>>(x, ws, packed);
  vq_combine<<<NTOK / 256, 256, 0, stream>>>(x, emb, packed, out, ws + WS_LOSS);
  vq_finish<<<1, 1, 0, stream>>>(ws + WS_LOSS, out);
}